// Round 1
// baseline (122.735 us; speedup 1.0000x reference)
//
#include <hip/hip_runtime.h>
#include <hip/hip_bf16.h>
#include <cstddef>

// Problem constants
#define BB 131072
#define DD 64
#define NREL 32

// Fixed-capacity binning: mean 4096/bin, sigma~63; +512 slack = ~8 sigma.
#define CAP 4608                 // 72 waves per bin
#define WPB (CAP / 64)           // 72
#define PERM_SLOTS (NREL * CAP)  // 147456
#define NWAVE (NREL * WPB)       // 2304 waves in phase D

#define BLOCKS_SC 512            // scatter blocks (256 thr, 1 sample/thread)

typedef __attribute__((ext_vector_type(8))) __bf16 bf16x8;
typedef __attribute__((ext_vector_type(16))) float f32x16;

// ---------------- Prep: R -> transposed bf16 hi/lo tables + cursor init -------
// Rt[r][n][k] layout so a B-fragment (n fixed, k contiguous) is one 16B load.
__global__ __launch_bounds__(256) void prep_kernel(
    const float* __restrict__ relE, __bf16* __restrict__ RtH,
    __bf16* __restrict__ RtL, int* __restrict__ cursor) {
  __shared__ float sR[64 * 65];
  const int r = blockIdx.x;
  const int t = threadIdx.x;
  if (t == 0) cursor[r] = r * CAP;  // bin base; after scatter, holds bin END
#pragma unroll
  for (int i = 0; i < 16; ++i) {
    const int idx = i * 256 + t;          // d*64 + e, coalesced read
    const int d = idx >> 6, e = idx & 63;
    sR[e * 65 + d] = relE[(size_t)r * 4096 + idx];  // stride-65: conflict-free
  }
  __syncthreads();
#pragma unroll
  for (int i = 0; i < 16; ++i) {
    const int idx = i * 256 + t;          // n*64 + k, coalesced write
    const float x = sR[(idx >> 6) * 65 + (idx & 63)];
    const __bf16 hb = (__bf16)x;
    RtH[(size_t)r * 4096 + idx] = hb;
    RtL[(size_t)r * 4096 + idx] = (__bf16)(x - (float)hb);
  }
}

// ---------------- Scatter: LDS rank + one global cursor reserve per (blk,bin) --
__global__ __launch_bounds__(256) void scatter_kernel(
    const int* __restrict__ rels, int* __restrict__ cursor,
    int* __restrict__ perm) {
  __shared__ int hist[NREL];
  __shared__ int base[NREL];
  const int t = threadIdx.x;
  if (t < NREL) hist[t] = 0;
  __syncthreads();
  const int s = blockIdx.x * 256 + t;
  const int rv = rels[s];
  const int rank = atomicAdd(&hist[rv], 1);
  __syncthreads();
  if (t < NREL) base[t] = atomicAdd(&cursor[t], hist[t]);
  __syncthreads();
  perm[base[rv] + rank] = s;   // order within bin is irrelevant
}

// ---------------- Phase D: MFMA bilinear, one wave per 64 bin-uniform samples --
// A-frags gathered DIRECTLY from e1g (no LDS staging): full 64B-line coverage.
// B-frags: precomputed transposed bf16 hi/lo (one dwordx4 each, L2-resident).
__global__ __launch_bounds__(64) void bilinear_mfma(
    const float* __restrict__ e1g, const float* __restrict__ e2g,
    const __bf16* __restrict__ RtH, const __bf16* __restrict__ RtL,
    const int* __restrict__ perm, const int* __restrict__ cursorEnd,
    float* __restrict__ out) {
  __shared__ float sP[64 * 33];
  const int lane = threadIdx.x;
  const int wb = blockIdx.x;
  const int r0 = wb / WPB;                // bin id (uniform)
  const int end = cursorEnd[r0];          // absolute end slot of this bin
  const int slotBase = wb * 64;
  if (slotBase >= end) return;            // fully-padded wave, uniform exit
  const int slot = slotBase + lane;
  const int pk = perm[slot];              // garbage if slot >= end (masked)
  const bool valid = slot < end;
  const int h = lane >> 5;
  const int l31 = lane & 31;

  // sample ids for A rows m = 32*ti + l31 (garbage rows masked to safe addr)
  int rowid[2];
  rowid[0] = __shfl(pk, l31) & 0x1FFFF;
  rowid[1] = __shfl(pk, 32 + l31) & 0x1FFFF;

  const __bf16* __restrict__ RH = RtH + (size_t)r0 * 4096;
  const __bf16* __restrict__ RL = RtL + (size_t)r0 * 4096;

  f32x16 acc[2][2];
#pragma unroll
  for (int ti = 0; ti < 2; ++ti)
#pragma unroll
    for (int tj = 0; tj < 2; ++tj)
#pragma unroll
      for (int i = 0; i < 16; ++i) acc[ti][tj][i] = 0.f;

#pragma unroll
  for (int kc = 0; kc < 4; ++kc) {
    bf16x8 aH[2], aL[2], bH[2], bL[2];
    // A[m=32ti+l31][k=kc*16+8h+j]: 2x float4 straight from global
#pragma unroll
    for (int ti = 0; ti < 2; ++ti) {
      const float* ap = e1g + (size_t)rowid[ti] * DD + kc * 16 + 8 * h;
      const float4 x0 = *(const float4*)(ap);
      const float4 x1 = *(const float4*)(ap + 4);
      const float xs[8] = {x0.x, x0.y, x0.z, x0.w, x1.x, x1.y, x1.z, x1.w};
#pragma unroll
      for (int j = 0; j < 8; ++j) {
        const __bf16 hb = (__bf16)xs[j];
        aH[ti][j] = hb;
        aL[ti][j] = (__bf16)(xs[j] - (float)hb);
      }
    }
    // B[k][n=32tj+l31]: transposed table => 8 contiguous bf16 = one 16B load
#pragma unroll
    for (int tj = 0; tj < 2; ++tj) {
      const size_t bo = (size_t)(32 * tj + l31) * DD + kc * 16 + 8 * h;
      bH[tj] = *(const bf16x8*)(RH + bo);
      bL[tj] = *(const bf16x8*)(RL + bo);
    }
#pragma unroll
    for (int ti = 0; ti < 2; ++ti)
#pragma unroll
      for (int tj = 0; tj < 2; ++tj) {
        acc[ti][tj] = __builtin_amdgcn_mfma_f32_32x32x16_bf16(aH[ti], bH[tj], acc[ti][tj], 0, 0, 0);
        acc[ti][tj] = __builtin_amdgcn_mfma_f32_32x32x16_bf16(aH[ti], bL[tj], acc[ti][tj], 0, 0, 0);
        acc[ti][tj] = __builtin_amdgcn_mfma_f32_32x32x16_bf16(aL[ti], bH[tj], acc[ti][tj], 0, 0, 0);
      }
  }

  // Epilogue: C row = 32ti + q + 8g + 4h, col = 32tj + l31.
  // v = acc[:,0]*E2[row][l31] + acc[:,1]*E2[row][l31+32], straight into LDS.
#pragma unroll
  for (int ti = 0; ti < 2; ++ti)
#pragma unroll
    for (int g = 0; g < 4; ++g)
#pragma unroll
      for (int q = 0; q < 4; ++q) {
        const int reg = g * 4 + q;
        const int rbase = 32 * ti + q + 8 * g;
        const int s0 = __builtin_amdgcn_readlane(pk, rbase) & 0x1FFFF;
        const int s1 = __builtin_amdgcn_readlane(pk, rbase + 4) & 0x1FFFF;
        const int bs = h ? s1 : s0;
        const float* er = e2g + (size_t)bs * DD + l31;
        const float v = fmaf(acc[ti][0][reg], er[0], acc[ti][1][reg] * er[32]);
        sP[(rbase + 4 * h) * 33 + l31] = v;   // stride-33: conflict-free
      }
  __syncthreads();
  float sc = 0.f;
#pragma unroll
  for (int c = 0; c < 32; ++c) sc += sP[lane * 33 + c];
  if (valid) out[pk] = sc;
}

extern "C" void kernel_launch(void* const* d_in, const int* in_sizes, int n_in,
                              void* d_out, int out_size, void* d_ws, size_t ws_size,
                              hipStream_t stream) {
  const float* e1 = (const float*)d_in[0];
  const float* e2 = (const float*)d_in[1];
  const int* rels = (const int*)d_in[2];
  const float* relE = (const float*)d_in[3];
  float* out = (float*)d_out;

  // Workspace: perm[147456] | cursor[32] | RtH bf16[131072] | RtL bf16[131072]
  int* perm = (int*)d_ws;
  int* cursor = perm + PERM_SLOTS;
  __bf16* RtH = (__bf16*)(cursor + NREL);   // byte offset 589952, 16B-aligned
  __bf16* RtL = RtH + NREL * 4096;

  prep_kernel<<<NREL, 256, 0, stream>>>(relE, RtH, RtL, cursor);
  scatter_kernel<<<BLOCKS_SC, 256, 0, stream>>>(rels, cursor, perm);
  bilinear_mfma<<<NWAVE, 64, 0, stream>>>(e1, e2, RtH, RtL, perm, cursor, out);
}

// Round 3
// 113.470 us; speedup vs baseline: 1.0817x; 1.0817x over previous
//
#include <hip/hip_runtime.h>
#include <hip/hip_bf16.h>
#include <cstddef>

// Problem constants
#define BB 131072
#define DD 64
#define NREL 32
#define PADN 133120            // BB + 2048 slack: bins padded to multiple of 64
#define NWAVE (PADN / 64)      // 2080 waves

// Sort phase decomposition
#define BLOCKS_AC 512
#define SPB (BB / BLOCKS_AC)   // 256 samples per block, 1 per thread
#define CHUNKS 8
#define BPC (BLOCKS_AC / CHUNKS)

typedef __attribute__((ext_vector_type(8))) __bf16 bf16x8;
typedef __attribute__((ext_vector_type(16))) float f32x16;

// ---------------- Phase A: per-block histogram + sentinel init of perm ----------
__global__ __launch_bounds__(256) void phaseA_hist(
    const int* __restrict__ rels, int* __restrict__ blockCnt,
    int* __restrict__ permPacked) {
  __shared__ int hist[NREL];
  const int t = threadIdx.x;
  if (t < NREL) hist[t] = 0;
  __syncthreads();
  const int gid = blockIdx.x * 256 + t;
  // sentinel-fill the padded perm buffer (overwritten by phaseC for real slots)
  permPacked[gid] = -1;
  if (gid < PADN - BB) permPacked[BB + gid] = -1;
  atomicAdd(&hist[rels[gid]], 1);
  __syncthreads();
  if (t < NREL) blockCnt[blockIdx.x * NREL + t] = hist[t];
}

// ---------------- Phase B: two-level scan; bin bases PADDED to multiple of 64 ---
__global__ __launch_bounds__(256) void phaseB_scan(
    const int* __restrict__ blockCnt, int* __restrict__ blockOff,
    int* __restrict__ binBase) {
  __shared__ int partial[CHUNKS][NREL];
  __shared__ int chunkBase[CHUNKS][NREL];
  __shared__ int binB[NREL];
  const int t = threadIdx.x;
  const int c = t >> 5;
  const int r = t & 31;
  const int b0 = c * BPC;
  int run = 0;
#pragma unroll 4
  for (int b = 0; b < BPC; ++b) run += blockCnt[(b0 + b) * NREL + r];
  partial[c][r] = run;
  __syncthreads();
  if (t < NREL) {
    int acc = 0;
#pragma unroll
    for (int i = 0; i < CHUNKS; ++i) { chunkBase[i][t] = acc; acc += partial[i][t]; }
  }
  __syncthreads();
  if (t == 0) {
    int acc = 0;
#pragma unroll
    for (int i = 0; i < NREL; ++i) {
      binB[i] = acc;
      const int tot = chunkBase[CHUNKS - 1][i] + partial[CHUNKS - 1][i];
      acc += (tot + 63) & ~63;   // pad each bin to full waves
    }
  }
  __syncthreads();
  if (t < NREL) binBase[t] = binB[t];
  int run2 = chunkBase[c][r];
#pragma unroll 4
  for (int b = 0; b < BPC; ++b) {
    blockOff[(b0 + b) * NREL + r] = run2;
    run2 += blockCnt[(b0 + b) * NREL + r];
  }
}

// ---------------- Phase C: scatter (rel<<17 | sample) into padded sorted order --
__global__ __launch_bounds__(256) void phaseC_scatter(
    const int* __restrict__ rels, const int* __restrict__ blockOff,
    const int* __restrict__ binBase, int* __restrict__ permPacked) {
  __shared__ int cnt[NREL];
  __shared__ int baseArr[NREL];
  const int t = threadIdx.x;
  if (t < NREL) {
    cnt[t] = 0;
    baseArr[t] = binBase[t] + blockOff[blockIdx.x * NREL + t];
  }
  __syncthreads();
  const int s = blockIdx.x * SPB + t;
  const int rv = rels[s];
  const int rank = atomicAdd(&cnt[rv], 1);
  permPacked[baseArr[rv] + rank] = (rv << 17) | s;
}

// ---------------- Phase D: MFMA bilinear, one wave per 64 rel-uniform samples ---
// A-frags gathered DIRECTLY from e1g (no LDS staging): lane (h,l31) reads two
// float4 of row[32ti+l31] -> one instruction covers 32 full 64B lines.
// B split hi/lo bf16 on the fly from clean, L2/L3-resident relE (3-mfma ~fp32).
__global__ __launch_bounds__(64) void bilinear_mfma(
    const float* __restrict__ e1g, const float* __restrict__ e2g,
    const float* __restrict__ relE, const int* __restrict__ permPacked,
    float* __restrict__ out) {
  __shared__ float sP[64 * 33];  // epilogue transpose only (8.4 KB)
  const int lane = threadIdx.x;
  const int pk = permPacked[blockIdx.x * 64 + lane];
  const unsigned long long vm = __ballot(pk >= 0);
  if (vm == 0ull) return;  // fully-padded wave (uniform exit, before barriers)
  const int fv = (int)__builtin_ctzll(vm);
  const int r0 = __builtin_amdgcn_readlane(pk, fv) >> 17;  // bin => rel uniform
  const int h = lane >> 5;
  const int l31 = lane & 31;
  // sample ids for A rows m = 32*ti + l31 (sentinel -1 => 0x1FFFF, safe addr)
  const int rowid0 = __shfl(pk, l31) & 0x1FFFF;
  const int rowid1 = __shfl(pk, 32 + l31) & 0x1FFFF;

  const float* __restrict__ R = relE + (size_t)r0 * (DD * DD);

  f32x16 acc[2][2];
#pragma unroll
  for (int ti = 0; ti < 2; ++ti)
#pragma unroll
    for (int tj = 0; tj < 2; ++tj)
#pragma unroll
      for (int i = 0; i < 16; ++i) acc[ti][tj][i] = 0.f;

#pragma unroll
  for (int kc = 0; kc < 4; ++kc) {
    bf16x8 aH[2], aL[2], bH[2], bL[2];
    // A[m=32ti+l31][k=16kc+8h+j]: two float4 direct from e1g
#pragma unroll
    for (int ti = 0; ti < 2; ++ti) {
      const float* ap =
          e1g + (size_t)(ti ? rowid1 : rowid0) * DD + kc * 16 + 8 * h;
      const float4 x0 = *(const float4*)(ap);
      const float4 x1 = *(const float4*)(ap + 4);
      const float xs[8] = {x0.x, x0.y, x0.z, x0.w, x1.x, x1.y, x1.z, x1.w};
#pragma unroll
      for (int j = 0; j < 8; ++j) {
        const __bf16 hb = (__bf16)xs[j];
        aH[ti][j] = hb;
        aL[ti][j] = (__bf16)(xs[j] - (float)hb);
      }
    }
    // B[k=16kc+8h+j][n=32tj+l31]: rows of R are 128B-coalesced across the wave
#pragma unroll
    for (int tj = 0; tj < 2; ++tj) {
      const float* q = R + (size_t)(kc * 16 + 8 * h) * DD + 32 * tj + l31;
#pragma unroll
      for (int j = 0; j < 8; ++j) {
        const float x = q[(size_t)j * DD];
        const __bf16 hb = (__bf16)x;
        bH[tj][j] = hb;
        bL[tj][j] = (__bf16)(x - (float)hb);
      }
    }
#pragma unroll
    for (int ti = 0; ti < 2; ++ti)
#pragma unroll
      for (int tj = 0; tj < 2; ++tj) {
        acc[ti][tj] = __builtin_amdgcn_mfma_f32_32x32x16_bf16(aH[ti], bH[tj], acc[ti][tj], 0, 0, 0);
        acc[ti][tj] = __builtin_amdgcn_mfma_f32_32x32x16_bf16(aH[ti], bL[tj], acc[ti][tj], 0, 0, 0);
        acc[ti][tj] = __builtin_amdgcn_mfma_f32_32x32x16_bf16(aL[ti], bH[tj], acc[ti][tj], 0, 0, 0);
      }
  }

  // Epilogue: C-layout row = 32ti + q + 8g + 4h, col = 32tj + l31.
  // v = acc[:,0]*E2[row][l31] + acc[:,1]*E2[row][l31+32], straight into LDS.
#pragma unroll
  for (int ti = 0; ti < 2; ++ti)
#pragma unroll
    for (int g = 0; g < 4; ++g)
#pragma unroll
      for (int q = 0; q < 4; ++q) {
        const int reg = g * 4 + q;  // row_in_tile = (reg&3) + 8*(reg>>2) + 4h
        const int rbase = 32 * ti + q + 8 * g;
        const int s0 = __builtin_amdgcn_readlane(pk, rbase) & 0x1FFFF;
        const int s1 = __builtin_amdgcn_readlane(pk, rbase + 4) & 0x1FFFF;
        const int bs = h ? s1 : s0;
        const float* er = e2g + (size_t)bs * DD + l31;
        const float v = fmaf(acc[ti][0][reg], er[0], acc[ti][1][reg] * er[32]);
        sP[(rbase + 4 * h) * 33 + l31] = v;   // stride-33: conflict-free
      }
  __syncthreads();  // single-wave block: cheap s_barrier, orders LDS
  float sc = 0.f;
#pragma unroll
  for (int c = 0; c < 32; ++c) sc += sP[lane * 33 + c];
  if (pk >= 0) out[pk & 0x1FFFF] = sc;
}

extern "C" void kernel_launch(void* const* d_in, const int* in_sizes, int n_in,
                              void* d_out, int out_size, void* d_ws, size_t ws_size,
                              hipStream_t stream) {
  const float* e1 = (const float*)d_in[0];
  const float* e2 = (const float*)d_in[1];
  const int* rels = (const int*)d_in[2];
  const float* relE = (const float*)d_in[3];
  float* out = (float*)d_out;

  // Workspace (ints): permPacked[PADN] | blockCnt[512*32] | blockOff[512*32] | binBase[32]
  int* permPacked = (int*)d_ws;
  int* blockCnt = permPacked + PADN;
  int* blockOff = blockCnt + BLOCKS_AC * NREL;
  int* binBase = blockOff + BLOCKS_AC * NREL;

  phaseA_hist<<<BLOCKS_AC, 256, 0, stream>>>(rels, blockCnt, permPacked);
  phaseB_scan<<<1, 256, 0, stream>>>(blockCnt, blockOff, binBase);
  phaseC_scatter<<<BLOCKS_AC, 256, 0, stream>>>(rels, blockOff, binBase, permPacked);
  bilinear_mfma<<<NWAVE, 64, 0, stream>>>(e1, e2, relE, permPacked, out);
}

// Round 4
// 110.570 us; speedup vs baseline: 1.1100x; 1.0262x over previous
//
#include <hip/hip_runtime.h>
#include <hip/hip_bf16.h>
#include <cstddef>

// Problem constants
#define BB 131072
#define DD 64
#define NREL 32
#define PADN 133120            // BB + 2048 slack: bins padded to multiple of 64
#define NWAVE (PADN / 64)      // 2080 waves

// Sort decomposition
#define BLOCKS_AC 512
#define CHUNKS 8
#define BPC (BLOCKS_AC / CHUNKS)   // 64 blocks per chunk

typedef __attribute__((ext_vector_type(8))) __bf16 bf16x8;
typedef __attribute__((ext_vector_type(16))) float f32x16;

// ---------------- Phase A: per-block histogram + sentinel init of perm ----------
__global__ __launch_bounds__(256) void phaseA_hist(
    const int* __restrict__ rels, int* __restrict__ blockCnt,
    int* __restrict__ permPacked) {
  __shared__ int hist[NREL];
  const int t = threadIdx.x;
  if (t < NREL) hist[t] = 0;
  __syncthreads();
  const int gid = blockIdx.x * 256 + t;
  // sentinel-fill the padded perm buffer (real slots overwritten by scatter)
  permPacked[gid] = -1;
  if (gid < PADN - BB) permPacked[BB + gid] = -1;
  atomicAdd(&hist[rels[gid]], 1);
  __syncthreads();
  if (t < NREL) blockCnt[blockIdx.x * NREL + t] = hist[t];
}

// ---------------- Phase C': per-block recomputed scan + scatter (no phase B) ---
// Every block reads the full blockCnt table (64KB, L2-resident) and derives its
// own exclusive intra-bin offset + padded bin bases. Deterministic, atomic-free.
__global__ __launch_bounds__(256) void scatter_scan(
    const int* __restrict__ rels, const int* __restrict__ blockCnt,
    int* __restrict__ permPacked) {
  __shared__ int sF[CHUNKS][NREL];   // chunk totals
  __shared__ int sPp[CHUNKS][NREL];  // chunk partial prefix (blocks < b)
  __shared__ int sTot[NREL];
  __shared__ int sS[NREL];           // this block's exclusive offset in bin
  __shared__ int sBase[NREL];        // padded bin bases
  __shared__ int cnt[NREL];
  const int t = threadIdx.x;
  const int b = blockIdx.x;
  const int c = t >> 5;
  const int r = t & 31;
  const int b0 = c * BPC;
  int F = 0, Pp = 0;
#pragma unroll 4
  for (int i = 0; i < BPC; ++i) {    // 32 consecutive ints/row: coalesced 128B
    const int v = blockCnt[(b0 + i) * NREL + r];
    F += v;
    if (b0 + i < b) Pp += v;
  }
  sF[c][r] = F;
  sPp[c][r] = Pp;
  if (t < NREL) cnt[t] = 0;
  __syncthreads();
  if (t < NREL) {
    int S = 0, T = 0;
#pragma unroll
    for (int c2 = 0; c2 < CHUNKS; ++c2) { S += sPp[c2][t]; T += sF[c2][t]; }
    sS[t] = S;
    sTot[t] = T;
  }
  __syncthreads();
  if (t < NREL) {
    int bb = 0;
    for (int r2 = 0; r2 < t; ++r2) bb += (sTot[r2] + 63) & ~63;  // pad bins
    sBase[t] = bb;
  }
  __syncthreads();
  const int s = b * 256 + t;
  const int rv = rels[s];
  const int rank = atomicAdd(&cnt[rv], 1);   // LDS atomic only
  permPacked[sBase[rv] + sS[rv] + rank] = (rv << 17) | s;
}

// ---------------- Phase D: MFMA bilinear, one wave per 64 rel-uniform samples ---
// (byte-identical to the verified R3 kernel)
__global__ __launch_bounds__(64) void bilinear_mfma(
    const float* __restrict__ e1g, const float* __restrict__ e2g,
    const float* __restrict__ relE, const int* __restrict__ permPacked,
    float* __restrict__ out) {
  __shared__ float sP[64 * 33];  // epilogue transpose only (8.4 KB)
  const int lane = threadIdx.x;
  const int pk = permPacked[blockIdx.x * 64 + lane];
  const unsigned long long vm = __ballot(pk >= 0);
  if (vm == 0ull) return;  // fully-padded wave (uniform exit, before barriers)
  const int fv = (int)__builtin_ctzll(vm);
  const int r0 = __builtin_amdgcn_readlane(pk, fv) >> 17;  // bin => rel uniform
  const int h = lane >> 5;
  const int l31 = lane & 31;
  // sample ids for A rows m = 32*ti + l31 (sentinel -1 => 0x1FFFF, safe addr)
  const int rowid0 = __shfl(pk, l31) & 0x1FFFF;
  const int rowid1 = __shfl(pk, 32 + l31) & 0x1FFFF;

  const float* __restrict__ R = relE + (size_t)r0 * (DD * DD);

  f32x16 acc[2][2];
#pragma unroll
  for (int ti = 0; ti < 2; ++ti)
#pragma unroll
    for (int tj = 0; tj < 2; ++tj)
#pragma unroll
      for (int i = 0; i < 16; ++i) acc[ti][tj][i] = 0.f;

#pragma unroll
  for (int kc = 0; kc < 4; ++kc) {
    bf16x8 aH[2], aL[2], bH[2], bL[2];
    // A[m=32ti+l31][k=16kc+8h+j]: two float4 direct from e1g
#pragma unroll
    for (int ti = 0; ti < 2; ++ti) {
      const float* ap =
          e1g + (size_t)(ti ? rowid1 : rowid0) * DD + kc * 16 + 8 * h;
      const float4 x0 = *(const float4*)(ap);
      const float4 x1 = *(const float4*)(ap + 4);
      const float xs[8] = {x0.x, x0.y, x0.z, x0.w, x1.x, x1.y, x1.z, x1.w};
#pragma unroll
      for (int j = 0; j < 8; ++j) {
        const __bf16 hb = (__bf16)xs[j];
        aH[ti][j] = hb;
        aL[ti][j] = (__bf16)(xs[j] - (float)hb);
      }
    }
    // B[k=16kc+8h+j][n=32tj+l31]: rows of R are 128B-coalesced across the wave
#pragma unroll
    for (int tj = 0; tj < 2; ++tj) {
      const float* q = R + (size_t)(kc * 16 + 8 * h) * DD + 32 * tj + l31;
#pragma unroll
      for (int j = 0; j < 8; ++j) {
        const float x = q[(size_t)j * DD];
        const __bf16 hb = (__bf16)x;
        bH[tj][j] = hb;
        bL[tj][j] = (__bf16)(x - (float)hb);
      }
    }
#pragma unroll
    for (int ti = 0; ti < 2; ++ti)
#pragma unroll
      for (int tj = 0; tj < 2; ++tj) {
        acc[ti][tj] = __builtin_amdgcn_mfma_f32_32x32x16_bf16(aH[ti], bH[tj], acc[ti][tj], 0, 0, 0);
        acc[ti][tj] = __builtin_amdgcn_mfma_f32_32x32x16_bf16(aH[ti], bL[tj], acc[ti][tj], 0, 0, 0);
        acc[ti][tj] = __builtin_amdgcn_mfma_f32_32x32x16_bf16(aL[ti], bH[tj], acc[ti][tj], 0, 0, 0);
      }
  }

  // Epilogue: C-layout row = 32ti + q + 8g + 4h, col = 32tj + l31.
  // v = acc[:,0]*E2[row][l31] + acc[:,1]*E2[row][l31+32], straight into LDS.
#pragma unroll
  for (int ti = 0; ti < 2; ++ti)
#pragma unroll
    for (int g = 0; g < 4; ++g)
#pragma unroll
      for (int q = 0; q < 4; ++q) {
        const int reg = g * 4 + q;  // row_in_tile = (reg&3) + 8*(reg>>2) + 4h
        const int rbase = 32 * ti + q + 8 * g;
        const int s0 = __builtin_amdgcn_readlane(pk, rbase) & 0x1FFFF;
        const int s1 = __builtin_amdgcn_readlane(pk, rbase + 4) & 0x1FFFF;
        const int bs = h ? s1 : s0;
        const float* er = e2g + (size_t)bs * DD + l31;
        const float v = fmaf(acc[ti][0][reg], er[0], acc[ti][1][reg] * er[32]);
        sP[(rbase + 4 * h) * 33 + l31] = v;   // stride-33: conflict-free
      }
  __syncthreads();  // single-wave block: cheap s_barrier, orders LDS
  float sc = 0.f;
#pragma unroll
  for (int c = 0; c < 32; ++c) sc += sP[lane * 33 + c];
  if (pk >= 0) out[pk & 0x1FFFF] = sc;
}

extern "C" void kernel_launch(void* const* d_in, const int* in_sizes, int n_in,
                              void* d_out, int out_size, void* d_ws, size_t ws_size,
                              hipStream_t stream) {
  const float* e1 = (const float*)d_in[0];
  const float* e2 = (const float*)d_in[1];
  const int* rels = (const int*)d_in[2];
  const float* relE = (const float*)d_in[3];
  float* out = (float*)d_out;

  // Workspace (ints): permPacked[PADN] | blockCnt[512*32]
  int* permPacked = (int*)d_ws;
  int* blockCnt = permPacked + PADN;

  phaseA_hist<<<BLOCKS_AC, 256, 0, stream>>>(rels, blockCnt, permPacked);
  scatter_scan<<<BLOCKS_AC, 256, 0, stream>>>(rels, blockCnt, permPacked);
  bilinear_mfma<<<NWAVE, 64, 0, stream>>>(e1, e2, relE, permPacked, out);
}